// Round 8
// baseline (299.490 us; speedup 1.0000x reference)
//
#include <hip/hip_runtime.h>

// Problem constants (B=16, T=512, N=2048, U=64) — all inputs/outputs FP32.
#define N_DIM 2048
#define U_DIM 64
#define M_DIM 8192   // B*T
#define K_DIM 2048   // = N

typedef __bf16 bf16x8 __attribute__((ext_vector_type(8)));
typedef float  floatx4 __attribute__((ext_vector_type(4)));
typedef unsigned short ushort8 __attribute__((ext_vector_type(8)));

#define AS1 __attribute__((address_space(1)))
#define AS3 __attribute__((address_space(3)))

__device__ __forceinline__ unsigned short f_to_bf16_rne(float f) {
    unsigned int x;
    __builtin_memcpy(&x, &f, 4);
    x += 0x7fffu + ((x >> 16) & 1u);
    return (unsigned short)(x >> 16);
}

// ---------------------------------------------------------------------------
// Kernel 1: wbar[k] = mean_i W[i,k]  (fp32), bmean = mean(b)
// ---------------------------------------------------------------------------
__global__ __launch_bounds__(256) void prep_kernel(
    const float* __restrict__ W, const float* __restrict__ b,
    float* __restrict__ wbar, float* __restrict__ bmean) {
    int k = blockIdx.x * 256 + threadIdx.x;
    float s = 0.f;
#pragma unroll
    for (int i = 0; i < U_DIM; ++i) s += W[i * N_DIM + k];
    wbar[k] = s * (1.f / U_DIM);

    if (blockIdx.x == 0 && threadIdx.x < 64) {
        float v = b[threadIdx.x];
#pragma unroll
        for (int off = 32; off > 0; off >>= 1) v += __shfl_down(v, off);
        if (threadIdx.x == 0) bmean[0] = v * (1.f / U_DIM);
    }
}

// ---------------------------------------------------------------------------
// Kernel 2 (merged): blocks [0, 2048): weff[j,k] = bf16(Adj[j,k]*wbar[k])
//                    blocks [2048, 10240): xbf = bf16(x)
// NOTE (R6): materializing xbf once is structurally required — fusing the
// cvt into GEMM A-staging re-reads x as fp32 16x (FETCH 139->313 MB).
// ---------------------------------------------------------------------------
__global__ __launch_bounds__(256) void weff_convx_kernel(
    const float* __restrict__ Adj, const float* __restrict__ wbar,
    unsigned short* __restrict__ weff,
    const float* __restrict__ x, unsigned short* __restrict__ xbf) {
    if (blockIdx.x < 2048) {
        long long idx = ((long long)blockIdx.x * 256 + threadIdx.x) * 8;
        int k = (int)(idx & (N_DIM - 1));
        floatx4 a0 = *(const floatx4*)(Adj + idx);
        floatx4 a1 = *(const floatx4*)(Adj + idx + 4);
        floatx4 w0 = *(const floatx4*)(wbar + k);
        floatx4 w1 = *(const floatx4*)(wbar + k + 4);
        ushort8 ov;
#pragma unroll
        for (int j = 0; j < 4; ++j) {
            ov[j]     = f_to_bf16_rne(a0[j] * w0[j]);
            ov[j + 4] = f_to_bf16_rne(a1[j] * w1[j]);
        }
        *(ushort8*)(weff + idx) = ov;
    } else {
        long long idx = ((long long)(blockIdx.x - 2048) * 256 + threadIdx.x) * 8;
        floatx4 a0 = *(const floatx4*)(x + idx);
        floatx4 a1 = *(const floatx4*)(x + idx + 4);
        ushort8 ov;
#pragma unroll
        for (int j = 0; j < 4; ++j) {
            ov[j]     = f_to_bf16_rne(a0[j]);
            ov[j + 4] = f_to_bf16_rne(a1[j]);
        }
        *(ushort8*)(xbf + idx) = ov;
    }
}

// Fallback converter for chunked path (small ws)
__global__ __launch_bounds__(256) void convx_kernel(
    const float* __restrict__ x, unsigned short* __restrict__ xbf) {
    long long idx = ((long long)blockIdx.x * 256 + threadIdx.x) * 8;
    floatx4 a0 = *(const floatx4*)(x + idx);
    floatx4 a1 = *(const floatx4*)(x + idx + 4);
    ushort8 ov;
#pragma unroll
    for (int j = 0; j < 4; ++j) {
        ov[j]     = f_to_bf16_rne(a0[j]);
        ov[j + 4] = f_to_bf16_rne(a1[j]);
    }
    *(ushort8*)(xbf + idx) = ov;
}

// ---------------------------------------------------------------------------
// Kernel 3: C[m,j] = sum_k A[m,k]*Bt[j,k] + bmean   (bf16 in, fp32 acc/out)
// 128x128 tile, BK=64, 4 waves; wave = 64x64 via 4x4 of mfma_f32_16x16x32.
// NEW (R8): A-fragments load DIRECTLY from global (bf16 xbf) into registers,
// ping-pong double-buffered — prefetched during iter k's MFMA phase, drained
// at iter k+1's first barrier (full MFMA phase of overlap). Only B goes
// through LDS (global_load_lds width=16, XOR swizzle slot = kc^(row&7),
// 0 conflicts measured R4). Barrier2 now drains 4 DMA/16 KB instead of
// 8 DMA/32 KB, and 4 of 8 ds_read_b128/iter are gone.
// ---------------------------------------------------------------------------
#define BM 128
#define BN 128
#define BK 64

__global__ __launch_bounds__(256) void gemm_bt_kernel(
    const unsigned short* __restrict__ A,    // [M, K] bf16 bits (xbf)
    const unsigned short* __restrict__ Bt,   // [N, K] bf16 bits (weff)
    const float* __restrict__ bmeanp,
    float* __restrict__ C,                   // [M, N] fp32
    int mtiles) {
    __shared__ __align__(16) unsigned short sB[BN * BK];  // 16 KB (B only)

    const int id    = blockIdx.x;
    const int xcd   = id & 7;
    const int local = id >> 3;
    const int nt    = xcd * 2 + (local & 1);   // 0..15
    const int mt    = local >> 1;              // 0..mtiles-1
    const int tile_m = mt * BM;
    const int tile_n = nt * BN;

    const int tid  = threadIdx.x;
    const int w    = tid >> 6;    // wave 0..3
    const int lane = tid & 63;

    const float bmean = bmeanp[0];

    // --- B staging: chunk = 8 rows of 128 B; wave w stages chunks w*4..w*4+3.
    const int srow_in = lane >> 3;                    // 0..7 row within chunk
    const int skc     = (lane & 7) ^ srow_in;         // swizzled fetch chunk
    const int scol    = skc * 8;
    const unsigned short* gB[4];
    unsigned short* lB[4];
#pragma unroll
    for (int i = 0; i < 4; ++i) {
        int c = w * 4 + i;
        gB[i] = Bt + (size_t)(tile_n + c * 8 + srow_in) * K_DIM + scol;
        lB[i] = &sB[c * 8 * BK];
    }

    // --- fragment geometry. 16x16x32 frag: m(n)=lane&15, k=(lane>>4)*8+j.
    const int wrow = (w >> 1) * 64;
    const int wcol = (w & 1) * 64;
    const int fr = lane & 15;
    const int fq = lane >> 4;          // 0..3

    // B frag read offsets in swizzled LDS
    int boff[4][2];
#pragma unroll
    for (int i = 0; i < 4; ++i)
#pragma unroll
        for (int s = 0; s < 2; ++s) {
            int kc = s * 4 + fq;
            int slot = kc ^ (fr & 7);
            boff[i][s] = (wcol + i * 16 + fr) * BK + slot * 8;
        }

    // A frag global base pointers (per mi): row = tile_m+wrow+mi*16+fr, k-base fq*8
    const unsigned short* pA[4];
#pragma unroll
    for (int mi = 0; mi < 4; ++mi)
        pA[mi] = A + (size_t)(tile_m + wrow + mi * 16 + fr) * K_DIM + fq * 8;

    floatx4 acc[4][4];
#pragma unroll
    for (int mi = 0; mi < 4; ++mi)
#pragma unroll
        for (int ni = 0; ni < 4; ++ni) acc[mi][ni] = (floatx4){0.f, 0.f, 0.f, 0.f};

    // ping-pong A register buffers; preload buffer 0 at k=0
    bf16x8 arA[4][2], arB[4][2];
#pragma unroll
    for (int mi = 0; mi < 4; ++mi) {
        arA[mi][0] = *(const bf16x8*)(pA[mi]);
        arA[mi][1] = *(const bf16x8*)(pA[mi] + 32);
    }

// One K-iteration: barrier; B-DMA(K0); barrier (drains B DMA + prior A
// prefetch); prefetch NXT A-regs at KPF (issued before MFMAs -> in flight
// through the whole MFMA phase); ds_read B + MFMA using CUR A-regs.
#define GEMM_STEP(K0, CUR, NXT, KPF, DO_PF)                                   \
    {                                                                         \
        __syncthreads();                                                      \
        _Pragma("unroll")                                                     \
        for (int i = 0; i < 4; ++i)                                           \
            __builtin_amdgcn_global_load_lds((const AS1 void*)(gB[i] + (K0)), \
                                             (AS3 void*)lB[i], 16, 0, 0);     \
        __syncthreads();                                                      \
        if (DO_PF) {                                                          \
            _Pragma("unroll")                                                 \
            for (int mi = 0; mi < 4; ++mi) {                                  \
                NXT[mi][0] = *(const bf16x8*)(pA[mi] + (KPF));                \
                NXT[mi][1] = *(const bf16x8*)(pA[mi] + (KPF) + 32);           \
            }                                                                 \
        }                                                                     \
        _Pragma("unroll")                                                     \
        for (int s = 0; s < 2; ++s) {                                         \
            bf16x8 bfr[4];                                                    \
            _Pragma("unroll")                                                 \
            for (int i = 0; i < 4; ++i)                                       \
                bfr[i] = *(const bf16x8*)&sB[boff[i][s]];                     \
            _Pragma("unroll")                                                 \
            for (int mi = 0; mi < 4; ++mi)                                    \
                _Pragma("unroll")                                             \
                for (int ni = 0; ni < 4; ++ni)                                \
                    acc[mi][ni] = __builtin_amdgcn_mfma_f32_16x16x32_bf16(    \
                        CUR[mi][s], bfr[ni], acc[mi][ni], 0, 0, 0);           \
        }                                                                     \
    }

    for (int k0 = 0; k0 < K_DIM; k0 += 2 * BK) {
        // phase 1: compute k0 with arA, prefetch k0+BK into arB (always valid)
        GEMM_STEP(k0, arA, arB, k0 + BK, 1);
        // phase 2: compute k0+BK with arB, prefetch k0+2BK into arA (guarded)
        GEMM_STEP(k0 + BK, arB, arA, k0 + 2 * BK, (k0 + 2 * BK < K_DIM));
    }
#undef GEMM_STEP

    // Epilogue. 16x16 C/D: col = lane&15, row = (lane>>4)*4 + reg  [m89/m91]
    const int crow = tile_m + wrow + fq * 4;
    const int ccol = tile_n + wcol + fr;
#pragma unroll
    for (int mi = 0; mi < 4; ++mi)
#pragma unroll
        for (int ni = 0; ni < 4; ++ni)
#pragma unroll
            for (int r = 0; r < 4; ++r) {
                int gm = crow + mi * 16 + r;
                int gn = ccol + ni * 16;
                C[(size_t)gm * N_DIM + gn] = acc[mi][ni][r] + bmean;
            }
    (void)mtiles;
}

// ---------------------------------------------------------------------------
extern "C" void kernel_launch(void* const* d_in, const int* in_sizes, int n_in,
                              void* d_out, int out_size, void* d_ws, size_t ws_size,
                              hipStream_t stream) {
    (void)in_sizes; (void)n_in; (void)out_size;
    const float* x   = (const float*)d_in[0];  // [16,512,2048]
    const float* Adj = (const float*)d_in[1];  // [2048,2048]
    const float* W   = (const float*)d_in[2];  // [64,2048]
    const float* b   = (const float*)d_in[3];  // [64]
    float* out = (float*)d_out;                // [16,512,2048] fp32

    // ws: wbar @0 (8 KB) | bmean @8192 | weff bf16 @16384 (8.39 MB) | xbf
    char* ws = (char*)d_ws;
    float* wbar  = (float*)ws;
    float* bmean = (float*)(ws + 8192);
    unsigned short* weff = (unsigned short*)(ws + 16384);
    const size_t weff_bytes = (size_t)N_DIM * N_DIM * 2;
    const size_t xbf_off = 16384 + weff_bytes;
    unsigned short* xbf = (unsigned short*)(ws + xbf_off);

    size_t avail = (ws_size > xbf_off) ? (ws_size - xbf_off) : 0;
    long long max_rows = (long long)(avail / ((size_t)K_DIM * 2)) / BM * BM;
    if (max_rows < BM) max_rows = BM;
    if (max_rows > M_DIM) max_rows = M_DIM;

    prep_kernel<<<N_DIM / 256, 256, 0, stream>>>(W, b, wbar, bmean);

    if (max_rows == M_DIM) {
        weff_convx_kernel<<<2048 + M_DIM, 256, 0, stream>>>(Adj, wbar, weff, x, xbf);
        gemm_bt_kernel<<<(N_DIM / BN) * (M_DIM / BM), 256, 0, stream>>>(
            xbf, weff, bmean, out, M_DIM / BM);
    } else {
        weff_convx_kernel<<<2048, 256, 0, stream>>>(Adj, wbar, weff, x, xbf);
        for (long long m0 = 0; m0 < M_DIM; m0 += max_rows) {
            long long rows = (M_DIM - m0 < max_rows) ? (M_DIM - m0) : max_rows;
            convx_kernel<<<(int)rows, 256, 0, stream>>>(x + m0 * K_DIM, xbf);
            gemm_bt_kernel<<<(N_DIM / BN) * (int)(rows / BM), 256, 0, stream>>>(
                xbf, weff, bmean, out + m0 * (size_t)N_DIM, (int)(rows / BM));
        }
    }
}